// Round 1
// 1032.658 us; speedup vs baseline: 1.0424x; 1.0424x over previous
//
#include <hip/hip_runtime.h>

// LSTM: B=512, T=1000, IN=39, H=64, OUT=48, gate order i,f,g,o.
// One block per batch row; thread = gate index (4H=256 threads).
// R2: weights as macro-generated NAMED registers (R1's arrays were scratch-
// demoted at VGPR_Count=80 -> every step re-streamed ~105KB/block from L2).
// R3: fix x-prefetch off-by-one.
// R4 (this round):
//   (a) VGPR_Count was STILL 80 -> allocator was rematerializing the weight
//       loads inside the t-loop (uncoalesced 156B/256B-strided lane reads,
//       ~104KB/CU/step through L1/L2). Pin every weight through an empty
//       asm volatile("" : "+v"(..)) so its def is non-rematerializable, and
//       clamp occupancy with amdgpu_waves_per_eu(2,2) (grid can only give
//       2 waves/EU anyway) so the allocator spends registers freely.
//   (b) dot products as float2 ext-vectors -> v_pk_fma_f32 (104 FMA -> 52
//       packed per thread per step; OUT proj 16 -> 8).

#define BB 512
#define TT 1000
#define INF 39
#define HH 64
#define OUTF 48
#define G4 (4 * HH)

typedef float v2f __attribute__((ext_vector_type(2)));

// ---- repeat lists ----
#define Q10(M) M(0) M(1) M(2) M(3) M(4) M(5) M(6) M(7) M(8) M(9)
#define Q16(M) M(0) M(1) M(2) M(3) M(4) M(5) M(6) M(7) \
               M(8) M(9) M(10) M(11) M(12) M(13) M(14) M(15)

__global__ __launch_bounds__(256)
__attribute__((amdgpu_waves_per_eu(2, 2)))
void lstm_fused_kernel(
    const float* __restrict__ x,      // [B,T,IN]
    const float* __restrict__ W_ih,   // [4H, IN]
    const float* __restrict__ W_hh,   // [4H, H]
    const float* __restrict__ b_ih,   // [4H]
    const float* __restrict__ b_hh,   // [4H]
    const float* __restrict__ W_out,  // [OUT, H]
    const float* __restrict__ b_out,  // [OUT]
    float* __restrict__ out)          // [B,T,OUT]
{
    const int b = blockIdx.x;
    const int tid = threadIdx.x;          // gate index in [0,256)

    __shared__ float xs[40];              // x_t broadcast (padded, xs[39]=0)
    __shared__ float hs[HH];              // h_t broadcast
    __shared__ float act[G4];             // gate activations

    // ---- one-time: weights into NAMED, PINNED registers ----
    const float* wih_ptr = W_ih + tid * INF;
    // 10 quads covering 40 (last lane zero-padded), split into v2f pairs
#define LOAD_IH4(q) v2f wiA##q, wiB##q; \
    wiA##q.x = wih_ptr[4*(q)]; \
    wiA##q.y = (4*(q)+1 < INF) ? wih_ptr[4*(q)+1] : 0.f; \
    wiB##q.x = (4*(q)+2 < INF) ? wih_ptr[4*(q)+2] : 0.f; \
    wiB##q.y = (4*(q)+3 < INF) ? wih_ptr[4*(q)+3] : 0.f; \
    asm volatile("" : "+v"(wiA##q), "+v"(wiB##q));
    Q10(LOAD_IH4)

    const float4* wh4p = (const float4*)(W_hh + tid * HH);  // 256B-aligned
#define LOAD_HH4(i) const float4 whq##i = wh4p[i]; \
    v2f whA##i = {whq##i.x, whq##i.y}; \
    v2f whB##i = {whq##i.z, whq##i.w}; \
    asm volatile("" : "+v"(whA##i), "+v"(whB##i));
    Q16(LOAD_HH4)

    float bias = b_ih[tid] + b_hh[tid];
    asm volatile("" : "+v"(bias));

    // output-projection slice: tid<192 -> (o = tid>>2, p = tid&3), 16 wts
    const int o = tid >> 2;
    const int p = tid & 3;
    v2f woA0, woB0, woA1, woB1, woA2, woB2, woA3, woB3;
    float bo = 0.f;
    if (tid < 4 * OUTF) {
        const float4* wop = (const float4*)(W_out + o * HH + p * 16); // 64B-aligned
        const float4 q0 = wop[0], q1 = wop[1], q2 = wop[2], q3 = wop[3];
        woA0 = (v2f){q0.x, q0.y}; woB0 = (v2f){q0.z, q0.w};
        woA1 = (v2f){q1.x, q1.y}; woB1 = (v2f){q1.z, q1.w};
        woA2 = (v2f){q2.x, q2.y}; woB2 = (v2f){q2.z, q2.w};
        woA3 = (v2f){q3.x, q3.y}; woB3 = (v2f){q3.z, q3.w};
        bo = b_out[o];
    } else {
        woA0 = woB0 = woA1 = woB1 = (v2f){0.f, 0.f};
        woA2 = woB2 = woA3 = woB3 = (v2f){0.f, 0.f};
    }
    asm volatile("" : "+v"(woA0), "+v"(woB0), "+v"(woA1), "+v"(woB1),
                     "+v"(woA2), "+v"(woB2), "+v"(woA3), "+v"(woB3), "+v"(bo));

    float c = 0.f;                        // cell state, owned by tid<64
    const size_t x_base = (size_t)b * TT * INF;
    const size_t out_base = (size_t)b * TT * OUTF;

    if (tid < HH) hs[tid] = 0.f;
    if (tid < INF) xs[tid] = x[x_base + tid];
    if (tid == 39) xs[39] = 0.f;
    float xreg = (tid < INF) ? x[x_base + INF + tid] : 0.f;  // prefetch x_1

    const int gate_type = tid >> 6;       // wave-uniform: 0=i,1=f,2=g,3=o
    __syncthreads();                      // xs=x_0, hs=0 ready

    const float4* xs4 = (const float4*)xs;
    const float4* hs4 = (const float4*)hs;

    for (int t = 0; t < TT; ++t) {
        // ---- gate pre-activation: acc = bias + x.Wih_row + h.Whh_row ----
        v2f accA = {bias, 0.f};
        v2f accB = {0.f, 0.f};
#define FMA_IH4(q) { const float4 xv = xs4[q]; \
        const v2f xA = {xv.x, xv.y}; const v2f xB = {xv.z, xv.w}; \
        accA += xA * wiA##q; accB += xB * wiB##q; }
        Q10(FMA_IH4)
#define FMA_HH4(i) { const float4 hv = hs4[i]; \
        const v2f hA = {hv.x, hv.y}; const v2f hB = {hv.z, hv.w}; \
        accA += hA * whA##i; accB += hB * whB##i; }
        Q16(FMA_HH4)
        const float acc = (accA.x + accA.y) + (accB.x + accB.y);

        float a;
        if (gate_type == 2) {             // tanh (wave-uniform branch)
            a = 2.f / (1.f + __expf(-2.f * acc)) - 1.f;
        } else {                          // sigmoid
            a = 1.f / (1.f + __expf(-acc));
        }
        act[tid] = a;
        __syncthreads();                  // A: act ready; xs/hs reads done

        // stage x_{t+1}; refill prefetch with x_{t+2} (consumed after barrier B)
        if (tid < INF) {
            xs[tid] = xreg;
            if (t + 2 < TT) xreg = x[x_base + (size_t)(t + 2) * INF + tid];
        }
        if (tid < HH) {
            const float ig = act[tid];
            const float fg = act[HH + tid];
            const float gg = act[2 * HH + tid];
            const float og = act[3 * HH + tid];
            c = fg * c + ig * gg;
            const float th = 2.f / (1.f + __expf(-2.f * c)) - 1.f;
            hs[tid] = og * th;
        }
        __syncthreads();                  // B: hs = h_t, xs = x_{t+1}

        // ---- output projection y_t = sigmoid(h_t . W_out_row + b) ----
        if (tid < 4 * OUTF) {
            const float4 h0 = hs4[p * 4 + 0];
            const float4 h1 = hs4[p * 4 + 1];
            const float4 h2 = hs4[p * 4 + 2];
            const float4 h3 = hs4[p * 4 + 3];
            v2f sA = {0.f, 0.f}, sB = {0.f, 0.f};
            { const v2f a2 = {h0.x, h0.y}; const v2f b2 = {h0.z, h0.w};
              sA += a2 * woA0; sB += b2 * woB0; }
            { const v2f a2 = {h1.x, h1.y}; const v2f b2 = {h1.z, h1.w};
              sA += a2 * woA1; sB += b2 * woB1; }
            { const v2f a2 = {h2.x, h2.y}; const v2f b2 = {h2.z, h2.w};
              sA += a2 * woA2; sB += b2 * woB2; }
            { const v2f a2 = {h3.x, h3.y}; const v2f b2 = {h3.z, h3.w};
              sA += a2 * woA3; sB += b2 * woB3; }
            float s = (sA.x + sA.y) + (sB.x + sB.y);
            s += __shfl_xor(s, 1, 64);
            s += __shfl_xor(s, 2, 64);
            if (p == 0) {
                const float y = 1.f / (1.f + __expf(-(s + bo)));
                __builtin_nontemporal_store(y, &out[out_base + (size_t)t * OUTF + o]);
            }
        }
    }
}

extern "C" void kernel_launch(void* const* d_in, const int* in_sizes, int n_in,
                              void* d_out, int out_size, void* d_ws, size_t ws_size,
                              hipStream_t stream) {
    const float* x     = (const float*)d_in[0];
    const float* W_ih  = (const float*)d_in[1];
    const float* W_hh  = (const float*)d_in[2];
    const float* b_ih  = (const float*)d_in[3];
    const float* b_hh  = (const float*)d_in[4];
    const float* W_out = (const float*)d_in[5];
    const float* b_out = (const float*)d_in[6];
    float* out = (float*)d_out;

    lstm_fused_kernel<<<dim3(BB), dim3(G4), 0, stream>>>(
        x, W_ih, W_hh, b_ih, b_hh, W_out, b_out, out);
}